// Round 3
// baseline (633.156 us; speedup 1.0000x reference)
//
#include <hip/hip_runtime.h>
#include <math.h>

#define T_STEPS 500
#define BATCH   64
#define S_DIM   64
#define A_DIM   16
#define OBS_D   32
#define CTL_D   8
#define H_DIM   30

#define LOG2PI 1.8378770664093453f

typedef float v2f __attribute__((ext_vector_type(2)));

__device__ __forceinline__ float wmax(float v){
  #pragma unroll
  for (int o = 32; o > 0; o >>= 1) v = fmaxf(v, __shfl_xor(v, o, 64));
  return v;
}
__device__ __forceinline__ float wsum(float v){
  #pragma unroll
  for (int o = 32; o > 0; o >>= 1) v += __shfl_xor(v, o, 64);
  return v;
}

template<int CTRL>
__device__ __forceinline__ float dpp_add(float v){
  int x = __builtin_amdgcn_update_dpp(0, __float_as_int(v), CTRL, 0xF, 0xF, true);
  return v + __int_as_float(x);
}
template<int CTRL>
__device__ __forceinline__ float dpp_max(float v){
  int x = __builtin_amdgcn_update_dpp(0, __float_as_int(v), CTRL, 0xF, 0xF, true);
  return fmaxf(v, __int_as_float(x));
}

// raw barrier: drain LDS/SMEM only — vmcnt (global loads/stores) stays in flight
#define BAR() do { \
  asm volatile("s_waitcnt lgkmcnt(0)" ::: "memory"); \
  __builtin_amdgcn_s_barrier(); \
  asm volatile("" ::: "memory"); \
  __builtin_amdgcn_sched_barrier(0); \
} while (0)

#define FOR16(X) X(0) X(1) X(2) X(3) X(4) X(5) X(6) X(7) X(8) X(9) X(10) X(11) X(12) X(13) X(14) X(15)

// ---------------- k_pre: Bp softmax (blocks 0..255) + logp_u/p_a (blocks 256..380) ----------------
__global__ __launch_bounds__(256) void k_pre(const float* __restrict__ Blog,
                                             const float* __restrict__ u,
                                             const float* __restrict__ ctl_mu,
                                             const float* __restrict__ ctl_lv,
                                             const float* __restrict__ ctl_tl,
                                             float* __restrict__ Bp,
                                             float* __restrict__ lup,
                                             float* __restrict__ pap){
  const int tid = threadIdx.x;
  if (blockIdx.x < 256){
    const int row  = blockIdx.x * 4 + (tid >> 6);
    const int lane = tid & 63;
    float v = Blog[row * 64 + lane];
    float m = wmax(v);
    float e = __expf(v - m);
    float s = wsum(e);
    Bp[row * 64 + lane] = e / s;
    return;
  }
  const int item = (blockIdx.x - 256) * 256 + tid;   // 125*256 = 32000
  const float* up = u + item * CTL_D;
  float uu[CTL_D];
  #pragma unroll
  for (int i = 0; i < CTL_D; i += 4){
    float4 v = *(const float4*)(up + i);
    uu[i] = v.x; uu[i+1] = v.y; uu[i+2] = v.z; uu[i+3] = v.w;
  }
  float lp[A_DIM];
  #pragma unroll
  for (int a = 0; a < A_DIM; ++a){
    float z[CTL_D];
    float acc = 0.f, lvs = 0.f;
    #pragma unroll
    for (int i = 0; i < CTL_D; ++i){
      float lvv = ctl_lv[a * CTL_D + i];
      lvs += lvv;
      float s = uu[i] - ctl_mu[a * CTL_D + i];
      #pragma unroll
      for (int jj = 0; jj < i; ++jj) s = fmaf(-ctl_tl[a * 64 + i * CTL_D + jj], z[jj], s);
      z[i] = s * __expf(-lvv);
      acc  = fmaf(z[i], z[i], acc);
    }
    lp[a] = -0.5f * acc - lvs - 0.5f * CTL_D * LOG2PI;
  }
  float m = -1e30f;
  #pragma unroll
  for (int a = 0; a < A_DIM; ++a) m = fmaxf(m, lp[a]);
  float e[A_DIM], se = 0.f;
  #pragma unroll
  for (int a = 0; a < A_DIM; ++a){ e[a] = __expf(lp[a] - m); se += e[a]; }
  float inv = 1.f / se;
  #pragma unroll
  for (int a = 0; a < A_DIM; ++a){
    lup[item * A_DIM + a] = lp[a];
    pap[item * A_DIM + a] = e[a] * inv;
  }
}

// ---------------- logp_o: forward substitution, L via wave-uniform (scalar) loads ----------------
__global__ __launch_bounds__(256) void k_logp_o(const float* __restrict__ o,
                                                const float* __restrict__ mu,
                                                const float* __restrict__ lv,
                                                const float* __restrict__ tl,
                                                float* __restrict__ lo_out){
  const int k = blockIdx.x;
  const float* __restrict__ Lk  = tl + k * OBS_D * OBS_D;
  const float* __restrict__ muk = mu + k * OBS_D;
  const float* __restrict__ lvk = lv + k * OBS_D;

  float dinv[OBS_D];
  float lvsum = 0.f;
  #pragma unroll
  for (int i = 0; i < OBS_D; ++i){
    float x = lvk[i];
    lvsum += x;
    dinv[i] = __expf(-x);
  }

  const int item = blockIdx.y * 256 + threadIdx.x;   // 125*256 = 32000
  const float* op = o + item * OBS_D;
  float d[OBS_D];
  #pragma unroll
  for (int i = 0; i < OBS_D; i += 4){
    float4 v = *(const float4*)(op + i);
    d[i]   = v.x - muk[i];
    d[i+1] = v.y - muk[i+1];
    d[i+2] = v.z - muk[i+2];
    d[i+3] = v.w - muk[i+3];
  }
  float z[OBS_D];
  float acc = 0.f;
  #pragma unroll
  for (int i = 0; i < OBS_D; ++i){
    float s0 = d[i], s1 = 0.f;
    #pragma unroll
    for (int jj = 0; jj + 1 < i; jj += 2){
      s0 = fmaf(-Lk[i * OBS_D + jj],     z[jj],     s0);
      s1 = fmaf(-Lk[i * OBS_D + jj + 1], z[jj + 1], s1);
    }
    if (i & 1) s0 = fmaf(-Lk[i * OBS_D + i - 1], z[i - 1], s0);
    float zz = (s0 + s1) * dinv[i];
    z[i] = zz;
    acc  = fmaf(zz, zz, acc);
  }
  lo_out[item * S_DIM + k] = -0.5f * acc - lvsum - 0.5f * OBS_D * LOG2PI;
}

// ---------------- k_vi: VI with its own Bp softmax (1 block) ----------------
__global__ __launch_bounds__(256, 1) void k_vi(const float* __restrict__ Blog,
                                               const float* __restrict__ obs_lv,
                                               const float* __restrict__ Clog,
                                               const float* __restrict__ tau,
                                               float* __restrict__ Qout){
  const int tid  = threadIdx.x;
  const int lane = tid & 63;
  __shared__ __align__(16) float Vs[S_DIM];
  __shared__ __align__(16) float Qlds[A_DIM][S_DIM];
  __shared__ float hs[H_DIM];

  float c  = Clog[lane];
  float cm = wmax(c);
  float cs = wsum(__expf(c - cm));
  float lseC = cm + __logf(cs);
  float sumLnCp = wsum(c) - 64.f * lseC;

  if (tid < 64){
    float t0   = tau[0];
    float rate = __expf(t0);
    float lg = 0.f;
    for (int i = 2; i <= lane; ++i) lg += __logf((float)i);
    float lh = (lane < H_DIM) ? ((float)lane * t0 - rate - lg) : -1e30f;
    float m  = wmax(lh);
    float e  = (lane < H_DIM) ? __expf(lh - m) : 0.f;
    float s  = wsum(e);
    if (lane < H_DIM) hs[lane] = e / s;
  }

  float4 Br[4][16];
  float R[4], Qc[4], Qa[4];
  const int r0 = tid * 4;
  #pragma unroll
  for (int rr = 0; rr < 4; ++rr){
    const float* p = Blog + (r0 + rr) * 64;
    float4 raw[16];
    float mr = -1e30f;
    #pragma unroll
    for (int q = 0; q < 16; ++q){
      float4 v = *(const float4*)(p + 4 * q);
      raw[q] = v;
      mr = fmaxf(mr, fmaxf(fmaxf(v.x, v.y), fmaxf(v.z, v.w)));
    }
    float s = 0.f, dot = 0.f;
    #pragma unroll
    for (int q = 0; q < 16; ++q){
      float4 v = raw[q];
      float4 e;
      e.x = __expf(v.x - mr); e.y = __expf(v.y - mr);
      e.z = __expf(v.z - mr); e.w = __expf(v.w - mr);
      s   += (e.x + e.y) + (e.z + e.w);
      dot += e.x * (v.x - mr) + e.y * (v.y - mr) + e.z * (v.z - mr) + e.w * (v.w - mr);
      raw[q] = e;
    }
    float inv = 1.f / s;
    float lns = __logf(s);
    #pragma unroll
    for (int q = 0; q < 16; ++q){
      float4 e = raw[q];
      Br[rr][q] = make_float4(e.x * inv, e.y * inv, e.z * inv, e.w * inv);
    }
    float negent = dot * inv - lns;   // sum_j p ln p

    int sidx = (r0 + rr) & 63;
    float oe = 0.f;
    const float* lvp = obs_lv + sidx * OBS_D;
    #pragma unroll
    for (int d = 0; d < OBS_D; d += 4){
      float4 v = *(const float4*)(lvp + d);
      oe += v.x + v.y + v.z + v.w;
    }
    oe += 0.5f * OBS_D * (1.f + LOG2PI);
    R[rr]  = -negent + sumLnCp - oe;
    Qc[rr] = R[rr];
  }
  __syncthreads();
  #pragma unroll
  for (int rr = 0; rr < 4; ++rr) Qa[rr] = hs[0] * R[rr];

  const int aQ = r0 >> 6, sQ = r0 & 63;
  for (int it = 1; it < H_DIM; ++it){
    *(float4*)(&Qlds[aQ][sQ]) = make_float4(Qc[0], Qc[1], Qc[2], Qc[3]);
    __syncthreads();
    if (tid < 64){
      float m = -1e30f;
      #pragma unroll
      for (int aa = 0; aa < A_DIM; ++aa) m = fmaxf(m, Qlds[aa][lane]);
      float ss = 0.f;
      #pragma unroll
      for (int aa = 0; aa < A_DIM; ++aa) ss += __expf(Qlds[aa][lane] - m);
      Vs[lane] = m + __logf(ss);
    }
    __syncthreads();
    float hw = hs[it];
    #pragma unroll
    for (int rr = 0; rr < 4; ++rr){
      float accA = 0.f, accB = 0.f;
      #pragma unroll
      for (int q = 0; q < 16; ++q){
        float4 v = *(const float4*)(&Vs[4 * q]);
        accA = fmaf(Br[rr][q].x, v.x, fmaf(Br[rr][q].y, v.y, accA));
        accB = fmaf(Br[rr][q].z, v.z, fmaf(Br[rr][q].w, v.w, accB));
      }
      Qc[rr] = R[rr] + accA + accB;
      Qa[rr] = fmaf(hw, Qc[rr], Qa[rr]);
    }
  }
  *(float4*)(Qout + r0) = make_float4(Qa[0], Qa[1], Qa[2], Qa[3]);
}

// ---------------- fused HMM scan: named-register Bp tile, raw barrier, DPP reductions ----------------
// Lane layout: so = lane&7 (s-octant), jj = lane>>3, j = 8*wave + jj.
__global__ __launch_bounds__(512, 2) void k_scan(const float* __restrict__ Bp,
                                                 const float* __restrict__ lo,
                                                 const float* __restrict__ pa,
                                                 const float* __restrict__ Dlog,
                                                 float* __restrict__ bseq){
  const int n   = blockIdx.x;
  const int tid = threadIdx.x;
  const int g   = tid >> 6;
  const int l   = tid & 63;
  const int so  = l & 7;
  const int jj  = l >> 3;
  const int j   = g * 8 + jj;

  __shared__ __align__(16) float b_lds[2][S_DIM];
  __shared__ __align__(16) float ps[2][8];
  __shared__ __align__(16) float ms[2][8];

  // ---- named register-resident Bp tile: Bq{A}_{q} = {Bp[A, 8so+2q, j], Bp[A, 8so+2q+1, j]} ----
  #define DECLQ(A) v2f Bq##A##_0, Bq##A##_1, Bq##A##_2, Bq##A##_3;
  FOR16(DECLQ)
  #define LOADQ(A) { const float* p = Bp + (A) * 4096 + (8 * so) * 64 + j; \
    v2f t0; t0.x = p[0];   t0.y = p[64];  Bq##A##_0 = t0; \
    v2f t1; t1.x = p[128]; t1.y = p[192]; Bq##A##_1 = t1; \
    v2f t2; t2.x = p[256]; t2.y = p[320]; Bq##A##_2 = t2; \
    v2f t3; t3.x = p[384]; t3.y = p[448]; Bq##A##_3 = t3; }
  FOR16(LOADQ)

  if (tid < 64){
    float dl = Dlog[l];
    float m = wmax(dl);
    float e = __expf(dl - m);
    float s = wsum(e);
    float b0 = e / s;
    b_lds[0][l] = b0;
    bseq[n * 64 + l] = b0;
  }
  if (tid < 8) ps[0][tid] = 0.125f;

  const float* lo_n = lo + n * 64;     // + t*4096 + j
  const float* pa_n = pa + n * 16;     // + t*1024 + a

  // depth-2 lo pipeline: loc = t, lo1 = t+1, lo2 being loaded = t+2
  float loc = lo_n[j];
  float lo1 = lo_n[4096 + j];

  { // ms[0] from loc
    float w = loc;
    w = dpp_max<0x128>(w);     // row_ror:8
    w = dpp_max<0x142>(w);     // row_bcast15
    w = dpp_max<0x143>(w);     // row_bcast31
    if (l == 48) ms[0][g] = w;
  }

  // pa: current (t) in named scalars, next prefetched in-loop
  #define DECLPA(A) float pac_##A, pan_##A;
  FOR16(DECLPA)
  #define LDPA0(A) pac_##A = pa_n[A];
  FOR16(LDPA0)

  __syncthreads();

  int cur = 0;
  for (int t = 0; t < T_STEPS; ++t){
    const int nxt = cur ^ 1;

    // ---- top-of-step prefetch (not drained by the in-loop barrier) ----
    const int t2 = (t + 2 < T_STEPS) ? (t + 2) : (T_STEPS - 1);
    float lo2 = lo_n[t2 * 4096 + j];
    { // wave-partial max of lo1 (data for step t+1) -> ms[nxt]
      float w = lo1;
      w = dpp_max<0x128>(w);
      w = dpp_max<0x142>(w);
      w = dpp_max<0x143>(w);
      if (l == 48) ms[nxt][g] = w;
    }
    const int t1 = (t + 1 < T_STEPS) ? (t + 1) : (T_STEPS - 1);
    const float* pa_t1 = pa_n + t1 * 1024;
    #define LDPAN(A) pan_##A = pa_t1[A];
    FOR16(LDPAN)

    // ---- lik scale: sum & max from previous step's per-wave partials ----
    float4 p0 = *(const float4*)&ps[cur][0];
    float4 p1 = *(const float4*)&ps[cur][4];
    float sum = ((p0.x + p0.y) + (p0.z + p0.w)) + ((p1.x + p1.y) + (p1.z + p1.w));
    float4 m0v = *(const float4*)&ms[cur][0];
    float4 m1v = *(const float4*)&ms[cur][4];
    float mo = fmaxf(fmaxf(fmaxf(m0v.x, m0v.y), fmaxf(m0v.z, m0v.w)),
                     fmaxf(fmaxf(m1v.x, m1v.y), fmaxf(m1v.z, m1v.w)));
    float lik = __expf(loc - mo) * __builtin_amdgcn_rcpf(sum);

    // ---- belief tile ----
    v2f b2_0, b2_1, b2_2, b2_3;
    {
      float4 t0 = *(const float4*)&b_lds[cur][8 * so];
      float4 t1v = *(const float4*)&b_lds[cur][8 * so + 4];
      b2_0.x = t0.x;  b2_0.y = t0.y;
      b2_1.x = t0.z;  b2_1.y = t0.w;
      b2_2.x = t1v.x; b2_2.y = t1v.y;
      b2_3.x = t1v.z; b2_3.y = t1v.w;
    }

    v2f pri2; pri2.x = 0.f; pri2.y = 0.f;
    #define FMAQ(A) { \
      v2f acc = Bq##A##_0 * b2_0; \
      acc = __builtin_elementwise_fma(Bq##A##_1, b2_1, acc); \
      acc = __builtin_elementwise_fma(Bq##A##_2, b2_2, acc); \
      acc = __builtin_elementwise_fma(Bq##A##_3, b2_3, acc); \
      v2f pav; pav.x = pac_##A; pav.y = pac_##A; \
      pri2 = __builtin_elementwise_fma(pav, acc, pri2); }
    FOR16(FMAQ)
    float pri = pri2.x + pri2.y;

    // butterfly over s-octants (xor 1, 2, then half-mirror) — all lanes get full prior[j]
    pri = dpp_add<0xB1>(pri);
    pri = dpp_add<0x4E>(pri);
    pri = dpp_add<0x141>(pri);

    float post = pri * lik;
    if (so == 0){
      b_lds[nxt][j] = post;
      bseq[(t + 1) * 4096 + n * 64 + j] = post;
    }

    // per-wave sum of post over jj -> ps[nxt]
    {
      float w = post;
      w = dpp_add<0x128>(w);
      w = dpp_add<0x142>(w);
      w = dpp_add<0x143>(w);
      if (l == 48) ps[nxt][g] = w;
    }

    // rotate pipelines
    loc = lo1; lo1 = lo2;
    #define CPPA(A) pac_##A = pan_##A;
    FOR16(CPPA)

    BAR();
    cur = nxt;
  }
}

// ---------------- epilogue: logp_pi + logp_obs, fully parallel over (t,n) ----------------
__global__ __launch_bounds__(256, 1) void k_out(const float* __restrict__ bseq,
                                                const float* __restrict__ Qg,
                                                const float* __restrict__ lo,
                                                const float* __restrict__ lu,
                                                float* __restrict__ out){
  __shared__ __align__(16) float Qs[A_DIM][S_DIM];
  const int tid = threadIdx.x;
  for (int i = tid; i < A_DIM * S_DIM; i += 256) Qs[i >> 6][i & 63] = Qg[i];
  __syncthreads();

  const int item = blockIdx.x * 256 + tid;   // t*64 + n
  float bs[64];
  const float* bp_ = bseq + item * 64;
  float bsum = 0.f;
  #pragma unroll
  for (int i = 0; i < 16; ++i){
    float4 v = *(const float4*)(bp_ + 4 * i);
    bs[4*i] = v.x; bs[4*i+1] = v.y; bs[4*i+2] = v.z; bs[4*i+3] = v.w;
    bsum += (v.x + v.y) + (v.z + v.w);
  }
  float binv = 1.0f / bsum;

  float G[A_DIM];
  #pragma unroll
  for (int a = 0; a < A_DIM; ++a){
    float acc = 0.f;
    #pragma unroll
    for (int s = 0; s < 64; ++s) acc = fmaf(bs[s], Qs[a][s], acc);
    G[a] = acc * binv;
  }
  const float* lup = lu + item * A_DIM;
  float m1 = -1e30f, m0 = -1e30f;
  float x1[A_DIM];
  #pragma unroll
  for (int a = 0; a < A_DIM; ++a){
    x1[a] = G[a] + lup[a];
    m1 = fmaxf(m1, x1[a]);
    m0 = fmaxf(m0, G[a]);
  }
  float e1 = 0.f, e0 = 0.f;
  #pragma unroll
  for (int a = 0; a < A_DIM; ++a){
    e1 += __expf(x1[a] - m1);
    e0 += __expf(G[a] - m0);
  }
  out[item] = (m1 + __logf(e1)) - (m0 + __logf(e0));

  // logp_obs: uses b[t+1] and lo[t]
  const float* bq = bseq + (item + 64) * 64;
  float bsum2 = 0.f;
  #pragma unroll
  for (int i = 0; i < 16; ++i){
    float4 v = *(const float4*)(bq + 4 * i);
    bs[4*i] = v.x; bs[4*i+1] = v.y; bs[4*i+2] = v.z; bs[4*i+3] = v.w;
    bsum2 += (v.x + v.y) + (v.z + v.w);
  }
  float inv2 = 1.0f / bsum2;
  const float* lop = lo + item * 64;
  float terms[64];
  float mt = -1e30f;
  #pragma unroll
  for (int i = 0; i < 16; ++i){
    float4 v = *(const float4*)(lop + 4 * i);
    float t0 = __logf(bs[4*i]   * inv2 + 1e-6f) * v.x;
    float t1 = __logf(bs[4*i+1] * inv2 + 1e-6f) * v.y;
    float t2 = __logf(bs[4*i+2] * inv2 + 1e-6f) * v.z;
    float t3 = __logf(bs[4*i+3] * inv2 + 1e-6f) * v.w;
    terms[4*i] = t0; terms[4*i+1] = t1; terms[4*i+2] = t2; terms[4*i+3] = t3;
    mt = fmaxf(mt, fmaxf(fmaxf(t0, t1), fmaxf(t2, t3)));
  }
  float es = 0.f;
  #pragma unroll
  for (int s = 0; s < 64; ++s) es += __expf(terms[s] - mt);
  out[T_STEPS * BATCH + item] = mt + __logf(es);
}

extern "C" void kernel_launch(void* const* d_in, const int* in_sizes, int n_in,
                              void* d_out, int out_size, void* d_ws, size_t ws_size,
                              hipStream_t stream){
  const float* o      = (const float*)d_in[0];
  const float* u      = (const float*)d_in[1];
  const float* obs_mu = (const float*)d_in[2];
  const float* obs_lv = (const float*)d_in[3];
  const float* obs_tl = (const float*)d_in[4];
  const float* ctl_mu = (const float*)d_in[5];
  const float* ctl_lv = (const float*)d_in[6];
  const float* ctl_tl = (const float*)d_in[7];
  const float* Blog   = (const float*)d_in[8];
  const float* Dlog   = (const float*)d_in[9];
  const float* Clog   = (const float*)d_in[10];
  const float* tau    = (const float*)d_in[11];
  float* out = (float*)d_out;
  float* ws  = (float*)d_ws;

  float* Bp   = ws;                    // 65536
  float* Q    = ws + 65536;            // 1024
  float* lo   = ws + 66560;            // 2,048,000
  float* lu   = ws + 2114560;          // 512,000
  float* pa   = ws + 2626560;          // 512,000
  float* bseq = ws + 3138560;          // 501*4096 = 2,052,096   (total ~20.8 MiB)

  k_pre   <<<381, 256, 0, stream>>>(Blog, u, ctl_mu, ctl_lv, ctl_tl, Bp, lu, pa);
  k_logp_o<<<dim3(64, 125), 256, 0, stream>>>(o, obs_mu, obs_lv, obs_tl, lo);
  k_vi    <<<1, 256, 0, stream>>>(Blog, obs_lv, Clog, tau, Q);
  k_scan  <<<64, 512, 0, stream>>>(Bp, lo, pa, Dlog, bseq);
  k_out   <<<125, 256, 0, stream>>>(bseq, Q, lo, lu, out);
}

// Round 4
// 482.326 us; speedup vs baseline: 1.3127x; 1.3127x over previous
//
#include <hip/hip_runtime.h>
#include <math.h>

#define T_STEPS 500
#define BATCH   64
#define S_DIM   64
#define A_DIM   16
#define OBS_D   32
#define CTL_D   8
#define H_DIM   30

#define LOG2PI 1.8378770664093453f

typedef float v2f __attribute__((ext_vector_type(2)));

__device__ __forceinline__ float wmax(float v){
  #pragma unroll
  for (int o = 32; o > 0; o >>= 1) v = fmaxf(v, __shfl_xor(v, o, 64));
  return v;
}
__device__ __forceinline__ float wsum(float v){
  #pragma unroll
  for (int o = 32; o > 0; o >>= 1) v += __shfl_xor(v, o, 64);
  return v;
}

template<int CTRL>
__device__ __forceinline__ float dpp_add(float v){
  int x = __builtin_amdgcn_update_dpp(0, __float_as_int(v), CTRL, 0xF, 0xF, true);
  return v + __int_as_float(x);
}
template<int CTRL>
__device__ __forceinline__ float dpp_max(float v){
  int x = __builtin_amdgcn_update_dpp(0, __float_as_int(v), CTRL, 0xF, 0xF, true);
  return fmaxf(v, __int_as_float(x));
}

#define FOR16(X) X(0) X(1) X(2) X(3) X(4) X(5) X(6) X(7) X(8) X(9) X(10) X(11) X(12) X(13) X(14) X(15)

// ---------------- k_front: logp_o (bx<8000) + Bp softmax (<8256) + logp_u/p_a (<8381) ----------------
__global__ __launch_bounds__(256) void k_front(const float* __restrict__ o,
                                               const float* __restrict__ obs_mu,
                                               const float* __restrict__ obs_lv,
                                               const float* __restrict__ obs_tl,
                                               const float* __restrict__ Blog,
                                               const float* __restrict__ u,
                                               const float* __restrict__ ctl_mu,
                                               const float* __restrict__ ctl_lv,
                                               const float* __restrict__ ctl_tl,
                                               float* __restrict__ lo_out,
                                               float* __restrict__ Bp,
                                               float* __restrict__ lup,
                                               float* __restrict__ pap){
  const int bx  = blockIdx.x;
  const int tid = threadIdx.x;

  if (bx < 8000){
    // ---- logp_o: k = bx&63, item chunk = bx>>6 ----
    const int k = bx & 63;
    const float* __restrict__ Lk  = obs_tl + k * OBS_D * OBS_D;
    const float* __restrict__ muk = obs_mu + k * OBS_D;
    const float* __restrict__ lvk = obs_lv + k * OBS_D;

    float dinv[OBS_D];
    float lvsum = 0.f;
    #pragma unroll
    for (int i = 0; i < OBS_D; ++i){
      float x = lvk[i];
      lvsum += x;
      dinv[i] = __expf(-x);
    }

    const int item = (bx >> 6) * 256 + tid;   // 125*256 = 32000
    const float* op = o + item * OBS_D;
    float d[OBS_D];
    #pragma unroll
    for (int i = 0; i < OBS_D; i += 4){
      float4 v = *(const float4*)(op + i);
      d[i]   = v.x - muk[i];
      d[i+1] = v.y - muk[i+1];
      d[i+2] = v.z - muk[i+2];
      d[i+3] = v.w - muk[i+3];
    }
    float z[OBS_D];
    float acc = 0.f;
    #pragma unroll
    for (int i = 0; i < OBS_D; ++i){
      float s0 = d[i], s1 = 0.f;
      #pragma unroll
      for (int jj = 0; jj + 1 < i; jj += 2){
        s0 = fmaf(-Lk[i * OBS_D + jj],     z[jj],     s0);
        s1 = fmaf(-Lk[i * OBS_D + jj + 1], z[jj + 1], s1);
      }
      if (i & 1) s0 = fmaf(-Lk[i * OBS_D + i - 1], z[i - 1], s0);
      float zz = (s0 + s1) * dinv[i];
      z[i] = zz;
      acc  = fmaf(zz, zz, acc);
    }
    lo_out[item * S_DIM + k] = -0.5f * acc - lvsum - 0.5f * OBS_D * LOG2PI;
    return;
  }

  if (bx < 8256){
    // ---- Bp softmax rows ----
    const int row  = (bx - 8000) * 4 + (tid >> 6);
    const int lane = tid & 63;
    float v = Blog[row * 64 + lane];
    float m = wmax(v);
    float e = __expf(v - m);
    float s = wsum(e);
    Bp[row * 64 + lane] = e / s;
    return;
  }

  // ---- logp_u + p_a ----
  const int item = (bx - 8256) * 256 + tid;   // 125*256 = 32000
  const float* up = u + item * CTL_D;
  float uu[CTL_D];
  #pragma unroll
  for (int i = 0; i < CTL_D; i += 4){
    float4 v = *(const float4*)(up + i);
    uu[i] = v.x; uu[i+1] = v.y; uu[i+2] = v.z; uu[i+3] = v.w;
  }
  float lp[A_DIM];
  #pragma unroll
  for (int a = 0; a < A_DIM; ++a){
    float z[CTL_D];
    float acc = 0.f, lvs = 0.f;
    #pragma unroll
    for (int i = 0; i < CTL_D; ++i){
      float lvv = ctl_lv[a * CTL_D + i];
      lvs += lvv;
      float s = uu[i] - ctl_mu[a * CTL_D + i];
      #pragma unroll
      for (int jj = 0; jj < i; ++jj) s = fmaf(-ctl_tl[a * 64 + i * CTL_D + jj], z[jj], s);
      z[i] = s * __expf(-lvv);
      acc  = fmaf(z[i], z[i], acc);
    }
    lp[a] = -0.5f * acc - lvs - 0.5f * CTL_D * LOG2PI;
  }
  float m = -1e30f;
  #pragma unroll
  for (int a = 0; a < A_DIM; ++a) m = fmaxf(m, lp[a]);
  float e[A_DIM], se = 0.f;
  #pragma unroll
  for (int a = 0; a < A_DIM; ++a){ e[a] = __expf(lp[a] - m); se += e[a]; }
  float inv = 1.f / se;
  #pragma unroll
  for (int a = 0; a < A_DIM; ++a){
    lup[item * A_DIM + a] = lp[a];
    pap[item * A_DIM + a] = e[a] * inv;
  }
}

// ---------------- k_vi: 1024 threads, 1 (a,s) row per thread — no spills ----------------
__global__ __launch_bounds__(1024, 1) void k_vi(const float* __restrict__ Blog,
                                                const float* __restrict__ obs_lv,
                                                const float* __restrict__ Clog,
                                                const float* __restrict__ tau,
                                                float* __restrict__ Qout){
  const int tid  = threadIdx.x;
  const int lane = tid & 63;
  __shared__ __align__(16) float Vs[S_DIM];
  __shared__ __align__(16) float Qlds[A_DIM][S_DIM];
  __shared__ float hs[H_DIM];

  // sum_j ln Cp[j] (wave-uniform; every wave computes it)
  float c  = Clog[lane];
  float cm = wmax(c);
  float cs = wsum(__expf(c - cm));
  float lseC = cm + __logf(cs);
  float sumLnCp = wsum(c) - 64.f * lseC;

  if (tid < 64){
    float t0   = tau[0];
    float rate = __expf(t0);
    float lg = 0.f;
    for (int i = 2; i <= lane; ++i) lg += __logf((float)i);
    float lh = (lane < H_DIM) ? ((float)lane * t0 - rate - lg) : -1e30f;
    float m  = wmax(lh);
    float e  = (lane < H_DIM) ? __expf(lh - m) : 0.f;
    float s  = wsum(e);
    if (lane < H_DIM) hs[lane] = e / s;
  }

  // this thread's row: softmax over Blog[a,s,:] kept in registers
  const int r = tid;               // a*64 + s
  const int a = r >> 6, s = r & 63;
  const float* p = Blog + r * 64;
  float4 raw[16];
  float mr = -1e30f;
  #pragma unroll
  for (int q = 0; q < 16; ++q){
    float4 v = *(const float4*)(p + 4 * q);
    raw[q] = v;
    mr = fmaxf(mr, fmaxf(fmaxf(v.x, v.y), fmaxf(v.z, v.w)));
  }
  float ssum = 0.f, dot = 0.f;
  #pragma unroll
  for (int q = 0; q < 16; ++q){
    float4 v = raw[q];
    float4 e;
    e.x = __expf(v.x - mr); e.y = __expf(v.y - mr);
    e.z = __expf(v.z - mr); e.w = __expf(v.w - mr);
    ssum += (e.x + e.y) + (e.z + e.w);
    dot  += e.x * (v.x - mr) + e.y * (v.y - mr) + e.z * (v.z - mr) + e.w * (v.w - mr);
    raw[q] = e;
  }
  float inv = 1.f / ssum;
  float lns = __logf(ssum);
  #pragma unroll
  for (int q = 0; q < 16; ++q){
    float4 e = raw[q];
    raw[q] = make_float4(e.x * inv, e.y * inv, e.z * inv, e.w * inv);
  }
  float negent = dot * inv - lns;   // sum_j p ln p

  float oe = 0.f;
  const float* lvp = obs_lv + s * OBS_D;
  #pragma unroll
  for (int dd = 0; dd < OBS_D; dd += 4){
    float4 v = *(const float4*)(lvp + dd);
    oe += v.x + v.y + v.z + v.w;
  }
  oe += 0.5f * OBS_D * (1.f + LOG2PI);
  float R  = -negent + sumLnCp - oe;
  float Qc = R;
  __syncthreads();
  float Qa = hs[0] * R;

  for (int it = 1; it < H_DIM; ++it){
    Qlds[a][s] = Qc;
    __syncthreads();
    if (tid < 64){
      float m = -1e30f;
      #pragma unroll
      for (int aa = 0; aa < A_DIM; ++aa) m = fmaxf(m, Qlds[aa][lane]);
      float sv = 0.f;
      #pragma unroll
      for (int aa = 0; aa < A_DIM; ++aa) sv += __expf(Qlds[aa][lane] - m);
      Vs[lane] = m + __logf(sv);
    }
    __syncthreads();
    float hw = hs[it];
    float accA = 0.f, accB = 0.f;
    #pragma unroll
    for (int q = 0; q < 16; ++q){
      float4 v = *(const float4*)(&Vs[4 * q]);
      accA = fmaf(raw[q].x, v.x, fmaf(raw[q].y, v.y, accA));
      accB = fmaf(raw[q].z, v.z, fmaf(raw[q].w, v.w, accB));
    }
    Qc = R + accA + accB;
    Qa = fmaf(hw, Qc, Qa);
  }
  Qout[r] = Qa;
}

// ---------------- fused HMM scan: asm-pinned Bp tile, DPP reductions ----------------
// Lane layout: so = lane&7 (s-octant), jj = lane>>3, j = 8*wave + jj.
__global__ __launch_bounds__(512, 1) void k_scan(const float* __restrict__ Bp,
                                                 const float* __restrict__ lo,
                                                 const float* __restrict__ pa,
                                                 const float* __restrict__ Dlog,
                                                 float* __restrict__ bseq){
  const int n   = blockIdx.x;
  const int tid = threadIdx.x;
  const int g   = tid >> 6;
  const int l   = tid & 63;
  const int so  = l & 7;
  const int jj  = l >> 3;
  const int j   = g * 8 + jj;

  __shared__ __align__(16) float b_lds[2][S_DIM];
  __shared__ __align__(16) float ps[2][8];
  __shared__ __align__(16) float ms[2][8];

  // ---- named register-resident Bp tile: Bq{A}_{q} = {Bp[A, 8so+2q, j], Bp[A, 8so+2q+1, j]} ----
  #define DECLQ(A) v2f Bq##A##_0, Bq##A##_1, Bq##A##_2, Bq##A##_3;
  FOR16(DECLQ)
  #define LOADQ(A) { const float* p = Bp + (A) * 4096 + (8 * so) * 64 + j; \
    v2f t0; t0.x = p[0];   t0.y = p[64];  Bq##A##_0 = t0; \
    v2f t1; t1.x = p[128]; t1.y = p[192]; Bq##A##_1 = t1; \
    v2f t2; t2.x = p[256]; t2.y = p[320]; Bq##A##_2 = t2; \
    v2f t3; t3.x = p[384]; t3.y = p[448]; Bq##A##_3 = t3; }
  FOR16(LOADQ)

  // ---- pin: opaque asm makes these non-rematerializable -> must stay in VGPRs ----
  #define PIN2(X) asm volatile("" : "+v"(X));
  #define PINQ(A) PIN2(Bq##A##_0) PIN2(Bq##A##_1) PIN2(Bq##A##_2) PIN2(Bq##A##_3)
  FOR16(PINQ)

  if (tid < 64){
    float dl = Dlog[l];
    float m = wmax(dl);
    float e = __expf(dl - m);
    float s = wsum(e);
    float b0 = e / s;
    b_lds[0][l] = b0;
    bseq[n * 64 + l] = b0;
  }
  if (tid < 8) ps[0][tid] = 0.125f;

  const float* lo_n = lo + n * 64;     // + t*4096 + j
  const float* pa_n = pa + n * 16;     // + t*1024 + a

  // depth-2 lo pipeline
  float loc = lo_n[j];
  float lo1 = lo_n[4096 + j];

  { // ms[0] from loc
    float w = loc;
    w = dpp_max<0x128>(w);     // row_ror:8
    w = dpp_max<0x142>(w);     // row_bcast15
    w = dpp_max<0x143>(w);     // row_bcast31
    if (l == 48) ms[0][g] = w;
  }

  #define DECLPA(A) float pac_##A, pan_##A;
  FOR16(DECLPA)
  #define LDPA0(A) pac_##A = pa_n[A];
  FOR16(LDPA0)

  __syncthreads();

  int cur = 0;
  for (int t = 0; t < T_STEPS; ++t){
    const int nxt = cur ^ 1;

    // ---- top-of-step prefetch ----
    const int t2 = (t + 2 < T_STEPS) ? (t + 2) : (T_STEPS - 1);
    float lo2 = lo_n[t2 * 4096 + j];
    {
      float w = lo1;
      w = dpp_max<0x128>(w);
      w = dpp_max<0x142>(w);
      w = dpp_max<0x143>(w);
      if (l == 48) ms[nxt][g] = w;
    }
    const int t1 = (t + 1 < T_STEPS) ? (t + 1) : (T_STEPS - 1);
    const float* pa_t1 = pa_n + t1 * 1024;
    #define LDPAN(A) pan_##A = pa_t1[A];
    FOR16(LDPAN)

    // ---- lik scale from previous step's per-wave partials ----
    float4 p0 = *(const float4*)&ps[cur][0];
    float4 p1 = *(const float4*)&ps[cur][4];
    float sum = ((p0.x + p0.y) + (p0.z + p0.w)) + ((p1.x + p1.y) + (p1.z + p1.w));
    float4 m0v = *(const float4*)&ms[cur][0];
    float4 m1v = *(const float4*)&ms[cur][4];
    float mo = fmaxf(fmaxf(fmaxf(m0v.x, m0v.y), fmaxf(m0v.z, m0v.w)),
                     fmaxf(fmaxf(m1v.x, m1v.y), fmaxf(m1v.z, m1v.w)));
    float lik = __expf(loc - mo) * __builtin_amdgcn_rcpf(sum);

    // ---- belief tile ----
    v2f b2_0, b2_1, b2_2, b2_3;
    {
      float4 t0  = *(const float4*)&b_lds[cur][8 * so];
      float4 t1v = *(const float4*)&b_lds[cur][8 * so + 4];
      b2_0.x = t0.x;  b2_0.y = t0.y;
      b2_1.x = t0.z;  b2_1.y = t0.w;
      b2_2.x = t1v.x; b2_2.y = t1v.y;
      b2_3.x = t1v.z; b2_3.y = t1v.w;
    }

    v2f pr0, pr1, pr2, pr3;
    pr0.x = 0.f; pr0.y = 0.f; pr1 = pr0; pr2 = pr0; pr3 = pr0;
    #define FMAQ(A, P) { \
      v2f acc = Bq##A##_0 * b2_0; \
      acc = __builtin_elementwise_fma(Bq##A##_1, b2_1, acc); \
      acc = __builtin_elementwise_fma(Bq##A##_2, b2_2, acc); \
      acc = __builtin_elementwise_fma(Bq##A##_3, b2_3, acc); \
      v2f pav; pav.x = pac_##A; pav.y = pac_##A; \
      P = __builtin_elementwise_fma(pav, acc, P); }
    FMAQ(0, pr0)  FMAQ(1, pr1)  FMAQ(2, pr2)  FMAQ(3, pr3)
    FMAQ(4, pr0)  FMAQ(5, pr1)  FMAQ(6, pr2)  FMAQ(7, pr3)
    FMAQ(8, pr0)  FMAQ(9, pr1)  FMAQ(10, pr2) FMAQ(11, pr3)
    FMAQ(12, pr0) FMAQ(13, pr1) FMAQ(14, pr2) FMAQ(15, pr3)
    v2f pri2 = (pr0 + pr1) + (pr2 + pr3);
    float pri = pri2.x + pri2.y;

    // butterfly over s-octants — all lanes get full prior[j]
    pri = dpp_add<0xB1>(pri);    // quad_perm xor1
    pri = dpp_add<0x4E>(pri);    // quad_perm xor2
    pri = dpp_add<0x141>(pri);   // row_half_mirror (xor7)

    float post = pri * lik;
    if (so == 0){
      b_lds[nxt][j] = post;
      bseq[(t + 1) * 4096 + n * 64 + j] = post;
    }

    // per-wave sum of post -> ps[nxt] (lane 48 holds full wave total)
    {
      float w = post;
      w = dpp_add<0x128>(w);
      w = dpp_add<0x142>(w);
      w = dpp_add<0x143>(w);
      if (l == 48) ps[nxt][g] = w;
    }

    // rotate pipelines
    loc = lo1; lo1 = lo2;
    #define CPPA(A) pac_##A = pan_##A;
    FOR16(CPPA)

    __syncthreads();
    cur = nxt;
  }
}

// ---------------- epilogue: logp_pi + logp_obs, fully parallel over (t,n) ----------------
__global__ __launch_bounds__(256, 1) void k_out(const float* __restrict__ bseq,
                                                const float* __restrict__ Qg,
                                                const float* __restrict__ lo,
                                                const float* __restrict__ lu,
                                                float* __restrict__ out){
  __shared__ __align__(16) float Qs[A_DIM][S_DIM];
  const int tid = threadIdx.x;
  for (int i = tid; i < A_DIM * S_DIM; i += 256) Qs[i >> 6][i & 63] = Qg[i];
  __syncthreads();

  const int item = blockIdx.x * 256 + tid;   // t*64 + n
  float bs[64];
  const float* bp_ = bseq + item * 64;
  float bsum = 0.f;
  #pragma unroll
  for (int i = 0; i < 16; ++i){
    float4 v = *(const float4*)(bp_ + 4 * i);
    bs[4*i] = v.x; bs[4*i+1] = v.y; bs[4*i+2] = v.z; bs[4*i+3] = v.w;
    bsum += (v.x + v.y) + (v.z + v.w);
  }
  float binv = 1.0f / bsum;

  float G[A_DIM];
  #pragma unroll
  for (int a = 0; a < A_DIM; ++a){
    float acc = 0.f;
    #pragma unroll
    for (int s = 0; s < 64; ++s) acc = fmaf(bs[s], Qs[a][s], acc);
    G[a] = acc * binv;
  }
  const float* lup = lu + item * A_DIM;
  float m1 = -1e30f, m0 = -1e30f;
  float x1[A_DIM];
  #pragma unroll
  for (int a = 0; a < A_DIM; ++a){
    x1[a] = G[a] + lup[a];
    m1 = fmaxf(m1, x1[a]);
    m0 = fmaxf(m0, G[a]);
  }
  float e1 = 0.f, e0 = 0.f;
  #pragma unroll
  for (int a = 0; a < A_DIM; ++a){
    e1 += __expf(x1[a] - m1);
    e0 += __expf(G[a] - m0);
  }
  out[item] = (m1 + __logf(e1)) - (m0 + __logf(e0));

  // logp_obs: uses b[t+1] and lo[t]
  const float* bq = bseq + (item + 64) * 64;
  float bsum2 = 0.f;
  #pragma unroll
  for (int i = 0; i < 16; ++i){
    float4 v = *(const float4*)(bq + 4 * i);
    bs[4*i] = v.x; bs[4*i+1] = v.y; bs[4*i+2] = v.z; bs[4*i+3] = v.w;
    bsum2 += (v.x + v.y) + (v.z + v.w);
  }
  float inv2 = 1.0f / bsum2;
  const float* lop = lo + item * 64;
  float terms[64];
  float mt = -1e30f;
  #pragma unroll
  for (int i = 0; i < 16; ++i){
    float4 v = *(const float4*)(lop + 4 * i);
    float t0 = __logf(bs[4*i]   * inv2 + 1e-6f) * v.x;
    float t1 = __logf(bs[4*i+1] * inv2 + 1e-6f) * v.y;
    float t2 = __logf(bs[4*i+2] * inv2 + 1e-6f) * v.z;
    float t3 = __logf(bs[4*i+3] * inv2 + 1e-6f) * v.w;
    terms[4*i] = t0; terms[4*i+1] = t1; terms[4*i+2] = t2; terms[4*i+3] = t3;
    mt = fmaxf(mt, fmaxf(fmaxf(t0, t1), fmaxf(t2, t3)));
  }
  float es = 0.f;
  #pragma unroll
  for (int s = 0; s < 64; ++s) es += __expf(terms[s] - mt);
  out[T_STEPS * BATCH + item] = mt + __logf(es);
}

extern "C" void kernel_launch(void* const* d_in, const int* in_sizes, int n_in,
                              void* d_out, int out_size, void* d_ws, size_t ws_size,
                              hipStream_t stream){
  const float* o      = (const float*)d_in[0];
  const float* u      = (const float*)d_in[1];
  const float* obs_mu = (const float*)d_in[2];
  const float* obs_lv = (const float*)d_in[3];
  const float* obs_tl = (const float*)d_in[4];
  const float* ctl_mu = (const float*)d_in[5];
  const float* ctl_lv = (const float*)d_in[6];
  const float* ctl_tl = (const float*)d_in[7];
  const float* Blog   = (const float*)d_in[8];
  const float* Dlog   = (const float*)d_in[9];
  const float* Clog   = (const float*)d_in[10];
  const float* tau    = (const float*)d_in[11];
  float* out = (float*)d_out;
  float* ws  = (float*)d_ws;

  float* Bp   = ws;                    // 65536
  float* Q    = ws + 65536;            // 1024
  float* lo   = ws + 66560;            // 2,048,000
  float* lu   = ws + 2114560;          // 512,000
  float* pa   = ws + 2626560;          // 512,000
  float* bseq = ws + 3138560;          // 501*4096 = 2,052,096   (total ~20.8 MiB)

  k_front<<<8381, 256, 0, stream>>>(o, obs_mu, obs_lv, obs_tl, Blog,
                                    u, ctl_mu, ctl_lv, ctl_tl, lo, Bp, lu, pa);
  k_vi   <<<1, 1024, 0, stream>>>(Blog, obs_lv, Clog, tau, Q);
  k_scan <<<64, 512, 0, stream>>>(Bp, lo, pa, Dlog, bseq);
  k_out  <<<125, 256, 0, stream>>>(bseq, Q, lo, lu, out);
}